// Round 10
// baseline (128.337 us; speedup 1.0000x reference)
//
#include <hip/hip_runtime.h>

#define N_TOK 4096
#define NH    4

typedef __attribute__((ext_vector_type(8))) short bf16x8;
typedef __attribute__((ext_vector_type(4))) short bf16x4;
typedef __attribute__((ext_vector_type(4))) float f32x4;

static constexpr float SCALE   = 0.17677669529663687f;  // 32^-0.5
static constexpr float QSCALE  = 0.25503632254435463f;  // SCALE * log2(e)
static constexpr float LAMBDA_ = 0.1f;
#define PSTRIDE 2112   // floats per (h,qt32,ks) partial record

__device__ __forceinline__ unsigned short bf_rne(float f) {
    unsigned u = __float_as_uint(f);
    u += 0x7FFF + ((u >> 16) & 1);
    return (unsigned short)(u >> 16);
}

// ---------------------------------------------------------------------------
// Kernel 1: qkv projection via MFMA with fused prep_w (verbatim R9, verified).
// kB / vT written in fragment-major layout (R9-verified bit-exact).
// ---------------------------------------------------------------------------
__global__ __launch_bounds__(256) void qkv_kernel(
    const float* __restrict__ x, const float* __restrict__ wsrc,
    unsigned short* __restrict__ qA, unsigned short* __restrict__ kB,
    unsigned short* __restrict__ vT)
{
    __shared__ __align__(16) float xf[16][132];
    __shared__ __align__(16) unsigned short xbh[16 * 136];
    __shared__ __align__(16) unsigned short xbl[16 * 136];
    __shared__ __align__(16) unsigned short qsh[2][16][64];
    __shared__ __align__(16) unsigned short ksh[2][16][64];
    __shared__ __align__(16) unsigned short vsh[2][32][16];

    const int t  = threadIdx.x;
    const int tg = blockIdx.x >> 1;
    const int rh = blockIdx.x & 1;            // row half: heads {2rh, 2rh+1}
    const int n0 = tg * 16;
    const int nh = n0 >> 8, nw = (n0 >> 4) & 15;
    const int xbase = nh * 2048 + nw * 64;

    #pragma unroll
    for (int k = 0; k < 4; ++k) {
        int idx = t + k * 256;                // 0..1023
        int pair = idx & 7, ch = idx >> 3;
        float4 f4 = *(const float4*)&x[(size_t)ch * 32768 + xbase + pair * 4];
        xf[pair * 2][ch]     = f4.x;
        xf[pair * 2 + 1][ch] = f4.z;
    }
    __syncthreads();
    #pragma unroll
    for (int k = 0; k < 8; ++k) {
        int idx = t + k * 256;
        int tok = idx & 15, ch = idx >> 4;
        float f = xf[tok][ch];
        unsigned u = __float_as_uint(f);
        float lo = f - __uint_as_float(u & 0xFFFF0000u);
        xbh[tok * 136 + ch] = (unsigned short)(u >> 16);
        xbl[tok * 136 + ch] = (unsigned short)(__float_as_uint(lo) >> 16);
    }
    __syncthreads();

    const int lane = t & 63;
    const int m    = lane & 15;
    const int quad = lane >> 4;
    const int w    = t >> 6;

    bf16x8 Bh[4], Bl[4];
    #pragma unroll
    for (int s = 0; s < 4; ++s) {
        Bh[s] = *(const bf16x8*)&xbh[m * 136 + s * 32 + quad * 8];
        Bl[s] = *(const bf16x8*)&xbl[m * 136 + s * 32 + quad * 8];
    }

    #pragma unroll
    for (int rt = 0; rt < 3; ++rt) {
        const int R0 = rh * 192 + w * 48 + rt * 16;
        const int row = R0 + m;
        const int rr_row = row % 96;
        const float sc = (rr_row < 32) ? QSCALE : 1.0f;
        const float* wp = wsrc + (size_t)row * 128;
        bf16x8 Ah[4], Al[4];
        #pragma unroll
        for (int s = 0; s < 4; ++s) {
            float4 f0 = *(const float4*)(wp + s * 32 + quad * 8);
            float4 f1 = *(const float4*)(wp + s * 32 + quad * 8 + 4);
            float fv[8] = {f0.x, f0.y, f0.z, f0.w, f1.x, f1.y, f1.z, f1.w};
            #pragma unroll
            for (int j = 0; j < 8; ++j) {
                float f = fv[j] * sc;
                unsigned u = __float_as_uint(f);
                float lo = f - __uint_as_float(u & 0xFFFF0000u);
                Ah[s][j] = (short)(unsigned short)(u >> 16);
                Al[s][j] = (short)(unsigned short)(__float_as_uint(lo) >> 16);
            }
        }
        f32x4 C = {0, 0, 0, 0};
        #pragma unroll
        for (int s = 0; s < 4; ++s) {
            C = __builtin_amdgcn_mfma_f32_16x16x32_bf16(Ah[s], Bh[s], C, 0, 0, 0);
            C = __builtin_amdgcn_mfma_f32_16x16x32_bf16(Al[s], Bh[s], C, 0, 0, 0);
            C = __builtin_amdgcn_mfma_f32_16x16x32_bf16(Ah[s], Bl[s], C, 0, 0, 0);
        }
        #pragma unroll
        for (int i = 0; i < 4; ++i) {
            int R  = R0 + quad * 4 + i;
            int hh = R / 96;
            int rr = R - hh * 96;
            int hl = hh & 1;
            float f = C[i];
            if (rr < 64) {
                unsigned u = __float_as_uint(f);
                float lo = f - __uint_as_float(u & 0xFFFF0000u);
                unsigned short hi16 = (unsigned short)(u >> 16);
                unsigned short lo16 = (unsigned short)(__float_as_uint(lo) >> 16);
                int part = (rr & 31) >> 4, d = rr & 15;
                if (rr < 32) {
                    qsh[hl][m][part * 32 + d]      = hi16;
                    qsh[hl][m][part * 32 + d + 16] = lo16;
                } else {
                    ksh[hl][m][part * 32 + d]      = hi16;
                    ksh[hl][m][part * 32 + d + 16] = lo16;
                }
            } else {
                vsh[hl][rr - 64][m] = bf_rne(f);
            }
        }
    }
    __syncthreads();

    {   // qA: per-token layout. kB: fragment-major layout.
        int rec = t >> 3, g = t & 7;
        int hl  = rec >> 4, i = rec & 15;
        int hh  = rh * 2 + hl;
        int n   = n0 + i;
        size_t qbase = ((size_t)hh * N_TOK + n) * 64 + g * 8;
        *(uint4*)(qA + qbase) = *(const uint4*)&qsh[hl][i][g * 8];

        int tile = n >> 6, ml = n & 63;
        int kh2 = ml >> 5, mlb = (ml >> 4) & 1, mm = ml & 15;
        int f = mlb * 2 + (g >> 2), qd = g & 3;
        size_t koff = (size_t)hh * 262144 + (size_t)tile * 4096
                    + ((kh2 * 4 + f) * 64 + qd * 16 + mm) * 8;
        *(uint4*)(kB + koff) = *(const uint4*)&ksh[hl][i][g * 8];
    }
    if (t < 128) {  // vT fragment-major: two 8B granule stores per thread
        int hl = t >> 6, d = (t >> 1) & 31, half = t & 1;
        int hh = rh * 2 + hl;
        int kb = (n0 >> 3) + half;
        int tile = kb >> 3, kbl = kb & 7;
        int kh2 = kbl >> 2;
        int vf  = ((kbl >> 1) & 1) * 2 + (d >> 4);
        int mm  = d & 15;
        size_t vbase = (size_t)hh * 131072 + (size_t)tile * 2048 + (kh2 * 4 + vf) * 256;
        int q0 = (kbl & 1) << 1;
        *(uint2*)(vT + vbase + (q0 * 16 + mm) * 4)       = *(const uint2*)&vsh[hl][d][half * 8];
        *(uint2*)(vT + vbase + ((q0 + 1) * 16 + mm) * 4) = *(const uint2*)&vsh[hl][d][half * 8 + 4];
    }
}

// ---------------------------------------------------------------------------
// Kernel 2: MFMA flash diff-attention v14 — cross-tile software pipeline.
// Pure instruction REORDER of the verified v13 (same ops, same accumulation
// trees, same tile order -> bit-exact): iteration t issues QK(t+1) (operands
// loaded one tile ago), then SM+PV(t) whose S-inputs were produced a full
// tile earlier. Every instruction's operands are >=1 tile old -> the
// QK->exp2 and load->use stalls (the measured ~49% idle) collapse.
// Double-buffered register sets with static names (rule #20), unrolled x2.
// Barrier-free, coalesced fragment-major direct loads (R9-verified).
// ---------------------------------------------------------------------------
__global__ __launch_bounds__(256) void flash_kernel(
    const unsigned short* __restrict__ qA, const unsigned short* __restrict__ kB,
    const unsigned short* __restrict__ vT, float* __restrict__ parts)
{
    __shared__ float Obuf[2][2][16][33];                    // [qt][br][r][d+pad]
    __shared__ float lbuf[2][2][16];

    const int t    = threadIdx.x;
    const int w    = t >> 6;
    const int lane = t & 63;
    const int m    = lane & 15;
    const int quad = lane >> 4;
    const int ks   = blockIdx.x & 1;
    const int qt   = (blockIdx.x >> 1) & 127;
    const int h    = blockIdx.x >> 8;
    const int qtile = w >> 1;                 // 0..1
    const int kh    = w & 1;                  // key half within tile
    const int qbase = qt * 32;

    for (int i = t; i < 2112; i += 256) ((float*)Obuf)[i] = 0.f;
    if (t < 64) ((float*)lbuf)[t] = 0.f;
    __syncthreads();   // protect Obuf init (only barrier besides readout)

    const unsigned short* qrec = qA + (size_t)(h * N_TOK + qbase + qtile * 16 + m) * 64;
    const bf16x8 zz = {0,0,0,0,0,0,0,0};
    bf16x8 Bq1h = *(const bf16x8*)(qrec + (quad & 1) * 8);
    bf16x8 Bq2h = *(const bf16x8*)(qrec + 32 + (quad & 1) * 8);
    bf16x8 Bq1l = (quad < 2) ? *(const bf16x8*)(qrec + 16 + quad * 8) : zz;
    bf16x8 Bq2l = (quad < 2) ? *(const bf16x8*)(qrec + 48 + quad * 8) : zz;

    f32x4 O1a = {0,0,0,0}, O1b = {0,0,0,0}, O2a = {0,0,0,0}, O2b = {0,0,0,0};
    float l1 = 0.f, l2 = 0.f;

    // fragment-major bases: K chunk (kh*4+f)*512 shorts, V chunk (kh*4+vf)*256
    const unsigned short* kt = kB + (size_t)h * 262144 + (size_t)ks * 131072;
    const unsigned short* vt = vT + (size_t)h * 131072 + (size_t)ks * 65536;
    const int kcb = kh * 2048 + lane * 8;     // + f*512 + tile*4096
    const int vcb = kh * 1024 + lane * 4;     // + vf*256 + tile*2048

    // register sets: K x2, V x2, S x2 (static names)
    bf16x8 K00, K01, K02, K03, K10, K11, K12, K13;
    bf16x4 V00_, V01_, V02_, V03_, V10_, V11_, V12_, V13_;
    f32x4 S0A1, S0B1, S0A2, S0B2, S1A1, S1B1, S1A2, S1B2;

#define LOADK(KS, TILE) {                                                      \
        const unsigned short* kp = kt + (size_t)(TILE) * 4096 + kcb;           \
        KS##0 = *(const bf16x8*)(kp);                                          \
        KS##1 = *(const bf16x8*)(kp + 512);                                    \
        KS##2 = *(const bf16x8*)(kp + 1024);                                   \
        KS##3 = *(const bf16x8*)(kp + 1536);                                   \
    }
#define LOADV(VS, TILE) {                                                      \
        const unsigned short* vp = vt + (size_t)(TILE) * 2048 + vcb;           \
        VS##0_ = *(const bf16x4*)(vp);                                         \
        VS##1_ = *(const bf16x4*)(vp + 256);                                   \
        VS##2_ = *(const bf16x4*)(vp + 512);                                   \
        VS##3_ = *(const bf16x4*)(vp + 768);                                   \
    }
    // K mapping (verbatim v13): K1_0=KS0, K2_0=KS1, K1_1=KS2, K2_1=KS3
#define QKPH(SS, KS) {                                                         \
        __builtin_amdgcn_s_setprio(1);                                         \
        SS##A1 = (f32x4){0,0,0,0}; SS##B1 = (f32x4){0,0,0,0};                  \
        SS##A2 = (f32x4){0,0,0,0}; SS##B2 = (f32x4){0,0,0,0};                  \
        SS##A1 = __builtin_amdgcn_mfma_f32_16x16x32_bf16(KS##0, Bq1h, SS##A1, 0, 0, 0); \
        SS##B1 = __builtin_amdgcn_mfma_f32_16x16x32_bf16(KS##2, Bq1h, SS##B1, 0, 0, 0); \
        SS##A1 = __builtin_amdgcn_mfma_f32_16x16x32_bf16(KS##0, Bq1l, SS##A1, 0, 0, 0); \
        SS##B1 = __builtin_amdgcn_mfma_f32_16x16x32_bf16(KS##2, Bq1l, SS##B1, 0, 0, 0); \
        SS##A2 = __builtin_amdgcn_mfma_f32_16x16x32_bf16(KS##1, Bq2h, SS##A2, 0, 0, 0); \
        SS##B2 = __builtin_amdgcn_mfma_f32_16x16x32_bf16(KS##3, Bq2h, SS##B2, 0, 0, 0); \
        SS##A2 = __builtin_amdgcn_mfma_f32_16x16x32_bf16(KS##1, Bq2l, SS##A2, 0, 0, 0); \
        SS##B2 = __builtin_amdgcn_mfma_f32_16x16x32_bf16(KS##3, Bq2l, SS##B2, 0, 0, 0); \
    }
    // V mapping (verbatim v13): V00=VS0_, V10=VS1_, V01=VS2_, V11=VS3_
#define PVPH(SS, VS) {                                                         \
        float pa0 = __builtin_amdgcn_exp2f(SS##A1[0]), pa1 = __builtin_amdgcn_exp2f(SS##A1[1]); \
        float pa2 = __builtin_amdgcn_exp2f(SS##A1[2]), pa3 = __builtin_amdgcn_exp2f(SS##A1[3]); \
        float pb0 = __builtin_amdgcn_exp2f(SS##B1[0]), pb1 = __builtin_amdgcn_exp2f(SS##B1[1]); \
        float pb2 = __builtin_amdgcn_exp2f(SS##B1[2]), pb3 = __builtin_amdgcn_exp2f(SS##B1[3]); \
        float qa0 = __builtin_amdgcn_exp2f(SS##A2[0]), qa1 = __builtin_amdgcn_exp2f(SS##A2[1]); \
        float qa2 = __builtin_amdgcn_exp2f(SS##A2[2]), qa3 = __builtin_amdgcn_exp2f(SS##A2[3]); \
        float qb0 = __builtin_amdgcn_exp2f(SS##B2[0]), qb1 = __builtin_amdgcn_exp2f(SS##B2[1]); \
        float qb2 = __builtin_amdgcn_exp2f(SS##B2[2]), qb3 = __builtin_amdgcn_exp2f(SS##B2[3]); \
        l1 += (pa0 + pa1) + (pa2 + pa3) + (pb0 + pb1) + (pb2 + pb3);           \
        l2 += (qa0 + qa1) + (qa2 + qa3) + (qb0 + qb1) + (qb2 + qb3);           \
        union { unsigned u[2]; bf16x4 v; } cA1, cB1, cA2, cB2;                 \
        cA1.u[0] = __builtin_amdgcn_perm(__float_as_uint(pa1), __float_as_uint(pa0), 0x07060302u); \
        cA1.u[1] = __builtin_amdgcn_perm(__float_as_uint(pa3), __float_as_uint(pa2), 0x07060302u); \
        cB1.u[0] = __builtin_amdgcn_perm(__float_as_uint(pb1), __float_as_uint(pb0), 0x07060302u); \
        cB1.u[1] = __builtin_amdgcn_perm(__float_as_uint(pb3), __float_as_uint(pb2), 0x07060302u); \
        cA2.u[0] = __builtin_amdgcn_perm(__float_as_uint(qa1), __float_as_uint(qa0), 0x07060302u); \
        cA2.u[1] = __builtin_amdgcn_perm(__float_as_uint(qa3), __float_as_uint(qa2), 0x07060302u); \
        cB2.u[0] = __builtin_amdgcn_perm(__float_as_uint(qb1), __float_as_uint(qb0), 0x07060302u); \
        cB2.u[1] = __builtin_amdgcn_perm(__float_as_uint(qb3), __float_as_uint(qb2), 0x07060302u); \
        O1a = __builtin_amdgcn_mfma_f32_16x16x16bf16_1k(cA1.v, VS##0_, O1a, 0, 0, 0); \
        O1b = __builtin_amdgcn_mfma_f32_16x16x16bf16_1k(cA1.v, VS##1_, O1b, 0, 0, 0); \
        O2a = __builtin_amdgcn_mfma_f32_16x16x16bf16_1k(cA2.v, VS##0_, O2a, 0, 0, 0); \
        O2b = __builtin_amdgcn_mfma_f32_16x16x16bf16_1k(cA2.v, VS##1_, O2b, 0, 0, 0); \
        O1a = __builtin_amdgcn_mfma_f32_16x16x16bf16_1k(cB1.v, VS##2_, O1a, 0, 0, 0); \
        O1b = __builtin_amdgcn_mfma_f32_16x16x16bf16_1k(cB1.v, VS##3_, O1b, 0, 0, 0); \
        O2a = __builtin_amdgcn_mfma_f32_16x16x16bf16_1k(cB2.v, VS##2_, O2a, 0, 0, 0); \
        O2b = __builtin_amdgcn_mfma_f32_16x16x16bf16_1k(cB2.v, VS##3_, O2b, 0, 0, 0); \
        __builtin_amdgcn_s_setprio(0);                                         \
    }

    // prologue: L(0), L(1)K, Q(0)
    LOADK(K0, 0); LOADK(K1, 1); LOADV(V0, 0);
    QKPH(S0, K0);

    // steady state: iteration t does L(t+2)K, L(t+1)V, Q(t+1), P(t)
    for (int tl = 0; tl < 30; tl += 2) {
        // even sub-iteration (tile tl)
        LOADK(K0, tl + 2);
        LOADV(V1, tl + 1);
        QKPH(S1, K1);
        PVPH(S0, V0);
        // odd sub-iteration (tile tl+1)
        LOADK(K1, tl + 3);
        LOADV(V0, tl + 2);
        QKPH(S0, K0);
        PVPH(S1, V1);
    }
    // epilogue: tiles 30, 31
    LOADV(V1, 31);
    QKPH(S1, K1);      // Q(31), K1 holds tile 31
    PVPH(S0, V0);      // P(30)
    PVPH(S1, V1);      // P(31)

#undef LOADK
#undef LOADV
#undef QKPH
#undef PVPH

    l1 += __shfl_xor(l1, 16, 64); l1 += __shfl_xor(l1, 32, 64);
    l2 += __shfl_xor(l2, 16, 64); l2 += __shfl_xor(l2, 32, 64);
    if (lane < 16) {
        atomicAdd(&lbuf[qtile][0][m], l1);
        atomicAdd(&lbuf[qtile][1][m], l2);
    }
    #pragma unroll
    for (int i = 0; i < 4; ++i) {
        int r = quad * 4 + i;
        atomicAdd(&Obuf[qtile][0][r][m],      O1a[i]);
        atomicAdd(&Obuf[qtile][0][r][16 + m], O1b[i]);
        atomicAdd(&Obuf[qtile][1][r][m],      O2a[i]);
        atomicAdd(&Obuf[qtile][1][r][16 + m], O2b[i]);
    }
    __syncthreads();

    float* dst = parts + (size_t)((h * 128 + qt) * 2 + ks) * PSTRIDE;
    for (int i = t; i < 1024; i += 256) {
        int r = i >> 5, d = i & 31;
        int qtl = r >> 4, rl = r & 15;
        dst[i]        = Obuf[qtl][0][rl][d];
        dst[1024 + i] = Obuf[qtl][1][rl][d];
    }
    if (t < 32) {
        int qtl = t >> 4, rl = t & 15;
        dst[2048 + t] = lbuf[qtl][0][rl];
        dst[2080 + t] = lbuf[qtl][1][rl];
    }
}

// ---------------------------------------------------------------------------
// Kernel 3: split-K merge + finalize, float4-vectorized (verbatim R9).
// ---------------------------------------------------------------------------
__global__ __launch_bounds__(256) void merge_kernel(
    const float* __restrict__ parts, float* __restrict__ out)
{
    int idx = blockIdx.x * 256 + threadIdx.x;     // 131072 threads
    int d4 = (idx & 7) * 4;
    int row = idx >> 3;
    int h = row >> 12, n = row & 4095;
    int qt = n >> 5, r = n & 31;
    const float* p0 = parts + (size_t)((h * 128 + qt) * 2) * PSTRIDE;
    const float* p1 = p0 + PSTRIDE;
    float4 a1 = *(const float4*)(p0 + r * 32 + d4);
    float4 b1 = *(const float4*)(p1 + r * 32 + d4);
    float4 a2 = *(const float4*)(p0 + 1024 + r * 32 + d4);
    float4 b2 = *(const float4*)(p1 + 1024 + r * 32 + d4);
    float l1 = p0[2048 + r] + p1[2048 + r];
    float l2 = p0[2080 + r] + p1[2080 + r];
    float4 o;
    o.x = (a1.x + b1.x) / l1 - LAMBDA_ * ((a2.x + b2.x) / l2);
    o.y = (a1.y + b1.y) / l1 - LAMBDA_ * ((a2.y + b2.y) / l2);
    o.z = (a1.z + b1.z) / l1 - LAMBDA_ * ((a2.z + b2.z) / l2);
    o.w = (a1.w + b1.w) / l1 - LAMBDA_ * ((a2.w + b2.w) / l2);
    *(float4*)(out + (size_t)idx * 4) = o;
}

extern "C" void kernel_launch(void* const* d_in, const int* in_sizes, int n_in,
                              void* d_out, int out_size, void* d_ws, size_t ws_size,
                              hipStream_t stream) {
    const float* x = (const float*)d_in[0];   // (1,128,32,32,32)
    const float* w = (const float*)d_in[1];   // (384,128)
    float* out = (float*)d_out;               // [h][n][32] flat

    unsigned short* qA = (unsigned short*)d_ws;               // 2 MB
    unsigned short* kB = qA + (size_t)NH * N_TOK * 64;        // 2 MB
    unsigned short* vT = kB + (size_t)NH * N_TOK * 64;        // 1 MB
    float* parts = (float*)(vT + (size_t)NH * 32 * N_TOK);    // 1024*2112*4B = 8.65 MB

    qkv_kernel<<<512, 256, 0, stream>>>(x, w, qA, kB, vT);
    flash_kernel<<<1024, 256, 0, stream>>>(qA, kB, vT, parts);
    merge_kernel<<<512, 256, 0, stream>>>(parts, out);
}

// Round 11
// 120.865 us; speedup vs baseline: 1.0618x; 1.0618x over previous
//
#include <hip/hip_runtime.h>

#define N_TOK 4096
#define NH    4

typedef __attribute__((ext_vector_type(8))) short bf16x8;
typedef __attribute__((ext_vector_type(4))) short bf16x4;
typedef __attribute__((ext_vector_type(4))) float f32x4;

static constexpr float SCALE   = 0.17677669529663687f;  // 32^-0.5
static constexpr float QSCALE  = 0.25503632254435463f;  // SCALE * log2(e)
static constexpr float LAMBDA_ = 0.1f;
#define PSTRIDE 2112   // floats per (h,qt32,ks) partial record

__device__ __forceinline__ unsigned short bf_rne(float f) {
    unsigned u = __float_as_uint(f);
    u += 0x7FFF + ((u >> 16) & 1);
    return (unsigned short)(u >> 16);
}

// ---------------------------------------------------------------------------
// Kernel 1: qkv projection via MFMA with fused prep_w (verbatim R9, verified).
// kB / vT written in fragment-major layout (R9-verified bit-exact).
// ---------------------------------------------------------------------------
__global__ __launch_bounds__(256) void qkv_kernel(
    const float* __restrict__ x, const float* __restrict__ wsrc,
    unsigned short* __restrict__ qA, unsigned short* __restrict__ kB,
    unsigned short* __restrict__ vT)
{
    __shared__ __align__(16) float xf[16][132];
    __shared__ __align__(16) unsigned short xbh[16 * 136];
    __shared__ __align__(16) unsigned short xbl[16 * 136];
    __shared__ __align__(16) unsigned short qsh[2][16][64];
    __shared__ __align__(16) unsigned short ksh[2][16][64];
    __shared__ __align__(16) unsigned short vsh[2][32][16];

    const int t  = threadIdx.x;
    const int tg = blockIdx.x >> 1;
    const int rh = blockIdx.x & 1;            // row half: heads {2rh, 2rh+1}
    const int n0 = tg * 16;
    const int nh = n0 >> 8, nw = (n0 >> 4) & 15;
    const int xbase = nh * 2048 + nw * 64;

    #pragma unroll
    for (int k = 0; k < 4; ++k) {
        int idx = t + k * 256;                // 0..1023
        int pair = idx & 7, ch = idx >> 3;
        float4 f4 = *(const float4*)&x[(size_t)ch * 32768 + xbase + pair * 4];
        xf[pair * 2][ch]     = f4.x;
        xf[pair * 2 + 1][ch] = f4.z;
    }
    __syncthreads();
    #pragma unroll
    for (int k = 0; k < 8; ++k) {
        int idx = t + k * 256;
        int tok = idx & 15, ch = idx >> 4;
        float f = xf[tok][ch];
        unsigned u = __float_as_uint(f);
        float lo = f - __uint_as_float(u & 0xFFFF0000u);
        xbh[tok * 136 + ch] = (unsigned short)(u >> 16);
        xbl[tok * 136 + ch] = (unsigned short)(__float_as_uint(lo) >> 16);
    }
    __syncthreads();

    const int lane = t & 63;
    const int m    = lane & 15;
    const int quad = lane >> 4;
    const int w    = t >> 6;

    bf16x8 Bh[4], Bl[4];
    #pragma unroll
    for (int s = 0; s < 4; ++s) {
        Bh[s] = *(const bf16x8*)&xbh[m * 136 + s * 32 + quad * 8];
        Bl[s] = *(const bf16x8*)&xbl[m * 136 + s * 32 + quad * 8];
    }

    #pragma unroll
    for (int rt = 0; rt < 3; ++rt) {
        const int R0 = rh * 192 + w * 48 + rt * 16;
        const int row = R0 + m;
        const int rr_row = row % 96;
        const float sc = (rr_row < 32) ? QSCALE : 1.0f;
        const float* wp = wsrc + (size_t)row * 128;
        bf16x8 Ah[4], Al[4];
        #pragma unroll
        for (int s = 0; s < 4; ++s) {
            float4 f0 = *(const float4*)(wp + s * 32 + quad * 8);
            float4 f1 = *(const float4*)(wp + s * 32 + quad * 8 + 4);
            float fv[8] = {f0.x, f0.y, f0.z, f0.w, f1.x, f1.y, f1.z, f1.w};
            #pragma unroll
            for (int j = 0; j < 8; ++j) {
                float f = fv[j] * sc;
                unsigned u = __float_as_uint(f);
                float lo = f - __uint_as_float(u & 0xFFFF0000u);
                Ah[s][j] = (short)(unsigned short)(u >> 16);
                Al[s][j] = (short)(unsigned short)(__float_as_uint(lo) >> 16);
            }
        }
        f32x4 C = {0, 0, 0, 0};
        #pragma unroll
        for (int s = 0; s < 4; ++s) {
            C = __builtin_amdgcn_mfma_f32_16x16x32_bf16(Ah[s], Bh[s], C, 0, 0, 0);
            C = __builtin_amdgcn_mfma_f32_16x16x32_bf16(Al[s], Bh[s], C, 0, 0, 0);
            C = __builtin_amdgcn_mfma_f32_16x16x32_bf16(Ah[s], Bl[s], C, 0, 0, 0);
        }
        #pragma unroll
        for (int i = 0; i < 4; ++i) {
            int R  = R0 + quad * 4 + i;
            int hh = R / 96;
            int rr = R - hh * 96;
            int hl = hh & 1;
            float f = C[i];
            if (rr < 64) {
                unsigned u = __float_as_uint(f);
                float lo = f - __uint_as_float(u & 0xFFFF0000u);
                unsigned short hi16 = (unsigned short)(u >> 16);
                unsigned short lo16 = (unsigned short)(__float_as_uint(lo) >> 16);
                int part = (rr & 31) >> 4, d = rr & 15;
                if (rr < 32) {
                    qsh[hl][m][part * 32 + d]      = hi16;
                    qsh[hl][m][part * 32 + d + 16] = lo16;
                } else {
                    ksh[hl][m][part * 32 + d]      = hi16;
                    ksh[hl][m][part * 32 + d + 16] = lo16;
                }
            } else {
                vsh[hl][rr - 64][m] = bf_rne(f);
            }
        }
    }
    __syncthreads();

    {   // qA: per-token layout. kB: fragment-major layout.
        int rec = t >> 3, g = t & 7;
        int hl  = rec >> 4, i = rec & 15;
        int hh  = rh * 2 + hl;
        int n   = n0 + i;
        size_t qbase = ((size_t)hh * N_TOK + n) * 64 + g * 8;
        *(uint4*)(qA + qbase) = *(const uint4*)&qsh[hl][i][g * 8];

        int tile = n >> 6, ml = n & 63;
        int kh2 = ml >> 5, mlb = (ml >> 4) & 1, mm = ml & 15;
        int f = mlb * 2 + (g >> 2), qd = g & 3;
        size_t koff = (size_t)hh * 262144 + (size_t)tile * 4096
                    + ((kh2 * 4 + f) * 64 + qd * 16 + mm) * 8;
        *(uint4*)(kB + koff) = *(const uint4*)&ksh[hl][i][g * 8];
    }
    if (t < 128) {  // vT fragment-major: two 8B granule stores per thread
        int hl = t >> 6, d = (t >> 1) & 31, half = t & 1;
        int hh = rh * 2 + hl;
        int kb = (n0 >> 3) + half;
        int tile = kb >> 3, kbl = kb & 7;
        int kh2 = kbl >> 2;
        int vf  = ((kbl >> 1) & 1) * 2 + (d >> 4);
        int mm  = d & 15;
        size_t vbase = (size_t)hh * 131072 + (size_t)tile * 2048 + (kh2 * 4 + vf) * 256;
        int q0 = (kbl & 1) << 1;
        *(uint2*)(vT + vbase + (q0 * 16 + mm) * 4)       = *(const uint2*)&vsh[hl][d][half * 8];
        *(uint2*)(vT + vbase + ((q0 + 1) * 16 + mm) * 4) = *(const uint2*)&vsh[hl][d][half * 8 + 4];
    }
}

// ---------------------------------------------------------------------------
// Kernel 2: MFMA flash diff-attention v13 (verbatim R9, verified 54 us) —
// barrier-free + coalesced fragment-major direct loads + register
// double-buffer prefetch. Per-wave FP program identical to verified v7.
// R10's deeper manual pipeline REGRESSED (VALU moves + occupancy); the
// 4-wave/SIMD hardware interleave already provides the cross-phase overlap.
// ---------------------------------------------------------------------------
__global__ __launch_bounds__(256, 4) void flash_kernel(
    const unsigned short* __restrict__ qA, const unsigned short* __restrict__ kB,
    const unsigned short* __restrict__ vT, float* __restrict__ parts)
{
    __shared__ float Obuf[2][2][16][33];                    // [qt][br][r][d+pad]
    __shared__ float lbuf[2][2][16];

    const int t    = threadIdx.x;
    const int w    = t >> 6;
    const int lane = t & 63;
    const int m    = lane & 15;
    const int quad = lane >> 4;
    const int ks   = blockIdx.x & 1;
    const int qt   = (blockIdx.x >> 1) & 127;
    const int h    = blockIdx.x >> 8;
    const int qtile = w >> 1;                 // 0..1
    const int kh    = w & 1;                  // key half within tile
    const int qbase = qt * 32;

    for (int i = t; i < 2112; i += 256) ((float*)Obuf)[i] = 0.f;
    if (t < 64) ((float*)lbuf)[t] = 0.f;
    __syncthreads();   // protect Obuf init (only barrier besides readout)

    const unsigned short* qrec = qA + (size_t)(h * N_TOK + qbase + qtile * 16 + m) * 64;
    const bf16x8 zz = {0,0,0,0,0,0,0,0};
    bf16x8 Bq1h = *(const bf16x8*)(qrec + (quad & 1) * 8);
    bf16x8 Bq2h = *(const bf16x8*)(qrec + 32 + (quad & 1) * 8);
    bf16x8 Bq1l = (quad < 2) ? *(const bf16x8*)(qrec + 16 + quad * 8) : zz;
    bf16x8 Bq2l = (quad < 2) ? *(const bf16x8*)(qrec + 48 + quad * 8) : zz;

    f32x4 O1a = {0,0,0,0}, O1b = {0,0,0,0}, O2a = {0,0,0,0}, O2b = {0,0,0,0};
    float l1 = 0.f, l2 = 0.f;

    // fragment-major bases: K chunk (kh*4+f)*512 shorts, V chunk (kh*4+vf)*256
    const unsigned short* kt = kB + (size_t)h * 262144 + (size_t)ks * 131072;
    const unsigned short* vt = vT + (size_t)h * 131072 + (size_t)ks * 65536;
    const int kcb = kh * 2048 + lane * 8;     // + f*512 + tile*4096
    const int vcb = kh * 1024 + lane * 4;     // + vf*256 + tile*2048

    bf16x8 Ka0, Ka1, Ka2, Ka3, Kb0, Kb1, Kb2, Kb3;
    bf16x4 Va0, Va1, Va2, Va3, Vb0, Vb1, Vb2, Vb3;

#define LOADSET(K0, K1, K2, K3, V0, V1, V2, V3, TILE)                          \
    {                                                                          \
        const unsigned short* kp = kt + (size_t)(TILE) * 4096 + kcb;           \
        const unsigned short* vp = vt + (size_t)(TILE) * 2048 + vcb;           \
        K0 = *(const bf16x8*)(kp);                                             \
        K1 = *(const bf16x8*)(kp + 512);                                       \
        K2 = *(const bf16x8*)(kp + 1024);                                      \
        K3 = *(const bf16x8*)(kp + 1536);                                      \
        V0 = *(const bf16x4*)(vp);                                             \
        V1 = *(const bf16x4*)(vp + 256);                                       \
        V2 = *(const bf16x4*)(vp + 512);                                       \
        V3 = *(const bf16x4*)(vp + 768);                                       \
    }

    auto compute = [&](bf16x8 K1_0, bf16x8 K2_0, bf16x8 K1_1, bf16x8 K2_1,
                       bf16x4 V00, bf16x4 V10, bf16x4 V01, bf16x4 V11) {
        __builtin_amdgcn_s_setprio(1);
        f32x4 sA1 = {0,0,0,0}, sA2 = {0,0,0,0};
        f32x4 sB1 = {0,0,0,0}, sB2 = {0,0,0,0};
        sA1 = __builtin_amdgcn_mfma_f32_16x16x32_bf16(K1_0, Bq1h, sA1, 0, 0, 0);
        sB1 = __builtin_amdgcn_mfma_f32_16x16x32_bf16(K1_1, Bq1h, sB1, 0, 0, 0);
        sA1 = __builtin_amdgcn_mfma_f32_16x16x32_bf16(K1_0, Bq1l, sA1, 0, 0, 0);
        sB1 = __builtin_amdgcn_mfma_f32_16x16x32_bf16(K1_1, Bq1l, sB1, 0, 0, 0);
        sA2 = __builtin_amdgcn_mfma_f32_16x16x32_bf16(K2_0, Bq2h, sA2, 0, 0, 0);
        sB2 = __builtin_amdgcn_mfma_f32_16x16x32_bf16(K2_1, Bq2h, sB2, 0, 0, 0);
        sA2 = __builtin_amdgcn_mfma_f32_16x16x32_bf16(K2_0, Bq2l, sA2, 0, 0, 0);
        sB2 = __builtin_amdgcn_mfma_f32_16x16x32_bf16(K2_1, Bq2l, sB2, 0, 0, 0);

        float pa0 = __builtin_amdgcn_exp2f(sA1[0]), pa1 = __builtin_amdgcn_exp2f(sA1[1]);
        float pa2 = __builtin_amdgcn_exp2f(sA1[2]), pa3 = __builtin_amdgcn_exp2f(sA1[3]);
        float pb0 = __builtin_amdgcn_exp2f(sB1[0]), pb1 = __builtin_amdgcn_exp2f(sB1[1]);
        float pb2 = __builtin_amdgcn_exp2f(sB1[2]), pb3 = __builtin_amdgcn_exp2f(sB1[3]);
        float qa0 = __builtin_amdgcn_exp2f(sA2[0]), qa1 = __builtin_amdgcn_exp2f(sA2[1]);
        float qa2 = __builtin_amdgcn_exp2f(sA2[2]), qa3 = __builtin_amdgcn_exp2f(sA2[3]);
        float qb0 = __builtin_amdgcn_exp2f(sB2[0]), qb1 = __builtin_amdgcn_exp2f(sB2[1]);
        float qb2 = __builtin_amdgcn_exp2f(sB2[2]), qb3 = __builtin_amdgcn_exp2f(sB2[3]);
        l1 += (pa0 + pa1) + (pa2 + pa3) + (pb0 + pb1) + (pb2 + pb3);
        l2 += (qa0 + qa1) + (qa2 + qa3) + (qb0 + qb1) + (qb2 + qb3);
        union { unsigned u[2]; bf16x4 v; } cA1, cB1, cA2, cB2;
        cA1.u[0] = __builtin_amdgcn_perm(__float_as_uint(pa1), __float_as_uint(pa0), 0x07060302u);
        cA1.u[1] = __builtin_amdgcn_perm(__float_as_uint(pa3), __float_as_uint(pa2), 0x07060302u);
        cB1.u[0] = __builtin_amdgcn_perm(__float_as_uint(pb1), __float_as_uint(pb0), 0x07060302u);
        cB1.u[1] = __builtin_amdgcn_perm(__float_as_uint(pb3), __float_as_uint(pb2), 0x07060302u);
        cA2.u[0] = __builtin_amdgcn_perm(__float_as_uint(qa1), __float_as_uint(qa0), 0x07060302u);
        cA2.u[1] = __builtin_amdgcn_perm(__float_as_uint(qa3), __float_as_uint(qa2), 0x07060302u);
        cB2.u[0] = __builtin_amdgcn_perm(__float_as_uint(qb1), __float_as_uint(qb0), 0x07060302u);
        cB2.u[1] = __builtin_amdgcn_perm(__float_as_uint(qb3), __float_as_uint(qb2), 0x07060302u);

        O1a = __builtin_amdgcn_mfma_f32_16x16x16bf16_1k(cA1.v, V00, O1a, 0, 0, 0);
        O1b = __builtin_amdgcn_mfma_f32_16x16x16bf16_1k(cA1.v, V10, O1b, 0, 0, 0);
        O2a = __builtin_amdgcn_mfma_f32_16x16x16bf16_1k(cA2.v, V00, O2a, 0, 0, 0);
        O2b = __builtin_amdgcn_mfma_f32_16x16x16bf16_1k(cA2.v, V10, O2b, 0, 0, 0);
        O1a = __builtin_amdgcn_mfma_f32_16x16x16bf16_1k(cB1.v, V01, O1a, 0, 0, 0);
        O1b = __builtin_amdgcn_mfma_f32_16x16x16bf16_1k(cB1.v, V11, O1b, 0, 0, 0);
        O2a = __builtin_amdgcn_mfma_f32_16x16x16bf16_1k(cB2.v, V01, O2a, 0, 0, 0);
        O2b = __builtin_amdgcn_mfma_f32_16x16x16bf16_1k(cB2.v, V11, O2b, 0, 0, 0);
        __builtin_amdgcn_s_setprio(0);
    };

    LOADSET(Ka0, Ka1, Ka2, Ka3, Va0, Va1, Va2, Va3, 0);
    for (int tile = 0; tile < 32; tile += 2) {
        LOADSET(Kb0, Kb1, Kb2, Kb3, Vb0, Vb1, Vb2, Vb3, tile + 1);
        compute(Ka0, Ka1, Ka2, Ka3, Va0, Va1, Va2, Va3);
        if (tile + 2 < 32)
            LOADSET(Ka0, Ka1, Ka2, Ka3, Va0, Va1, Va2, Va3, tile + 2);
        compute(Kb0, Kb1, Kb2, Kb3, Vb0, Vb1, Vb2, Vb3);
    }
#undef LOADSET

    l1 += __shfl_xor(l1, 16, 64); l1 += __shfl_xor(l1, 32, 64);
    l2 += __shfl_xor(l2, 16, 64); l2 += __shfl_xor(l2, 32, 64);
    if (lane < 16) {
        atomicAdd(&lbuf[qtile][0][m], l1);
        atomicAdd(&lbuf[qtile][1][m], l2);
    }
    #pragma unroll
    for (int i = 0; i < 4; ++i) {
        int r = quad * 4 + i;
        atomicAdd(&Obuf[qtile][0][r][m],      O1a[i]);
        atomicAdd(&Obuf[qtile][0][r][16 + m], O1b[i]);
        atomicAdd(&Obuf[qtile][1][r][m],      O2a[i]);
        atomicAdd(&Obuf[qtile][1][r][16 + m], O2b[i]);
    }
    __syncthreads();

    float* dst = parts + (size_t)((h * 128 + qt) * 2 + ks) * PSTRIDE;
    for (int i = t; i < 1024; i += 256) {
        int r = i >> 5, d = i & 31;
        int qtl = r >> 4, rl = r & 15;
        dst[i]        = Obuf[qtl][0][rl][d];
        dst[1024 + i] = Obuf[qtl][1][rl][d];
    }
    if (t < 32) {
        int qtl = t >> 4, rl = t & 15;
        dst[2048 + t] = lbuf[qtl][0][rl];
        dst[2080 + t] = lbuf[qtl][1][rl];
    }
}

// ---------------------------------------------------------------------------
// Kernel 3: split-K merge + finalize, float4-vectorized (verbatim R9).
// ---------------------------------------------------------------------------
__global__ __launch_bounds__(256) void merge_kernel(
    const float* __restrict__ parts, float* __restrict__ out)
{
    int idx = blockIdx.x * 256 + threadIdx.x;     // 131072 threads
    int d4 = (idx & 7) * 4;
    int row = idx >> 3;
    int h = row >> 12, n = row & 4095;
    int qt = n >> 5, r = n & 31;
    const float* p0 = parts + (size_t)((h * 128 + qt) * 2) * PSTRIDE;
    const float* p1 = p0 + PSTRIDE;
    float4 a1 = *(const float4*)(p0 + r * 32 + d4);
    float4 b1 = *(const float4*)(p1 + r * 32 + d4);
    float4 a2 = *(const float4*)(p0 + 1024 + r * 32 + d4);
    float4 b2 = *(const float4*)(p1 + 1024 + r * 32 + d4);
    float l1 = p0[2048 + r] + p1[2048 + r];
    float l2 = p0[2080 + r] + p1[2080 + r];
    float4 o;
    o.x = (a1.x + b1.x) / l1 - LAMBDA_ * ((a2.x + b2.x) / l2);
    o.y = (a1.y + b1.y) / l1 - LAMBDA_ * ((a2.y + b2.y) / l2);
    o.z = (a1.z + b1.z) / l1 - LAMBDA_ * ((a2.z + b2.z) / l2);
    o.w = (a1.w + b1.w) / l1 - LAMBDA_ * ((a2.w + b2.w) / l2);
    *(float4*)(out + (size_t)idx * 4) = o;
}

extern "C" void kernel_launch(void* const* d_in, const int* in_sizes, int n_in,
                              void* d_out, int out_size, void* d_ws, size_t ws_size,
                              hipStream_t stream) {
    const float* x = (const float*)d_in[0];   // (1,128,32,32,32)
    const float* w = (const float*)d_in[1];   // (384,128)
    float* out = (float*)d_out;               // [h][n][32] flat

    unsigned short* qA = (unsigned short*)d_ws;               // 2 MB
    unsigned short* kB = qA + (size_t)NH * N_TOK * 64;        // 2 MB
    unsigned short* vT = kB + (size_t)NH * N_TOK * 64;        // 1 MB
    float* parts = (float*)(vT + (size_t)NH * 32 * N_TOK);    // 1024*2112*4B = 8.65 MB

    qkv_kernel<<<512, 256, 0, stream>>>(x, w, qA, kB, vT);
    flash_kernel<<<1024, 256, 0, stream>>>(qA, kB, vT, parts);
    merge_kernel<<<512, 256, 0, stream>>>(parts, out);
}

// Round 12
// 119.732 us; speedup vs baseline: 1.0719x; 1.0095x over previous
//
#include <hip/hip_runtime.h>

#define N_TOK 4096
#define NH    4

typedef __attribute__((ext_vector_type(8))) short bf16x8;
typedef __attribute__((ext_vector_type(4))) short bf16x4;
typedef __attribute__((ext_vector_type(4))) float f32x4;

static constexpr float SCALE   = 0.17677669529663687f;  // 32^-0.5
static constexpr float QSCALE  = 0.25503632254435463f;  // SCALE * log2(e)
static constexpr float LAMBDA_ = 0.1f;
#define PSTRIDE 2112   // floats per (h,qt32,ks) partial record

__device__ __forceinline__ unsigned short bf_rne(float f) {
    unsigned u = __float_as_uint(f);
    u += 0x7FFF + ((u >> 16) & 1);
    return (unsigned short)(u >> 16);
}

// ---------------------------------------------------------------------------
// Kernel 1: qkv projection via MFMA with fused prep_w (R9-verified compute).
// kB fragment-major (R9-verified). vT fragment-PAIR-major: lane's vf and vf+1
// granules adjacent so flash loads V as 2x16B instead of 4x8B:
//   V_vf granule for lane L at  tile*2048 + kh*1024 + (vf>>1)*512 + L*8 + (vf&1)*4
// Pure address permutation of the same bf16 values -> bit-exact fragments.
// ---------------------------------------------------------------------------
__global__ __launch_bounds__(256) void qkv_kernel(
    const float* __restrict__ x, const float* __restrict__ wsrc,
    unsigned short* __restrict__ qA, unsigned short* __restrict__ kB,
    unsigned short* __restrict__ vT)
{
    __shared__ __align__(16) float xf[16][132];
    __shared__ __align__(16) unsigned short xbh[16 * 136];
    __shared__ __align__(16) unsigned short xbl[16 * 136];
    __shared__ __align__(16) unsigned short qsh[2][16][64];
    __shared__ __align__(16) unsigned short ksh[2][16][64];
    __shared__ __align__(16) unsigned short vsh[2][32][16];

    const int t  = threadIdx.x;
    const int tg = blockIdx.x >> 1;
    const int rh = blockIdx.x & 1;            // row half: heads {2rh, 2rh+1}
    const int n0 = tg * 16;
    const int nh = n0 >> 8, nw = (n0 >> 4) & 15;
    const int xbase = nh * 2048 + nw * 64;

    #pragma unroll
    for (int k = 0; k < 4; ++k) {
        int idx = t + k * 256;                // 0..1023
        int pair = idx & 7, ch = idx >> 3;
        float4 f4 = *(const float4*)&x[(size_t)ch * 32768 + xbase + pair * 4];
        xf[pair * 2][ch]     = f4.x;
        xf[pair * 2 + 1][ch] = f4.z;
    }
    __syncthreads();
    #pragma unroll
    for (int k = 0; k < 8; ++k) {
        int idx = t + k * 256;
        int tok = idx & 15, ch = idx >> 4;
        float f = xf[tok][ch];
        unsigned u = __float_as_uint(f);
        float lo = f - __uint_as_float(u & 0xFFFF0000u);
        xbh[tok * 136 + ch] = (unsigned short)(u >> 16);
        xbl[tok * 136 + ch] = (unsigned short)(__float_as_uint(lo) >> 16);
    }
    __syncthreads();

    const int lane = t & 63;
    const int m    = lane & 15;
    const int quad = lane >> 4;
    const int w    = t >> 6;

    bf16x8 Bh[4], Bl[4];
    #pragma unroll
    for (int s = 0; s < 4; ++s) {
        Bh[s] = *(const bf16x8*)&xbh[m * 136 + s * 32 + quad * 8];
        Bl[s] = *(const bf16x8*)&xbl[m * 136 + s * 32 + quad * 8];
    }

    #pragma unroll
    for (int rt = 0; rt < 3; ++rt) {
        const int R0 = rh * 192 + w * 48 + rt * 16;
        const int row = R0 + m;
        const int rr_row = row % 96;
        const float sc = (rr_row < 32) ? QSCALE : 1.0f;
        const float* wp = wsrc + (size_t)row * 128;
        bf16x8 Ah[4], Al[4];
        #pragma unroll
        for (int s = 0; s < 4; ++s) {
            float4 f0 = *(const float4*)(wp + s * 32 + quad * 8);
            float4 f1 = *(const float4*)(wp + s * 32 + quad * 8 + 4);
            float fv[8] = {f0.x, f0.y, f0.z, f0.w, f1.x, f1.y, f1.z, f1.w};
            #pragma unroll
            for (int j = 0; j < 8; ++j) {
                float f = fv[j] * sc;
                unsigned u = __float_as_uint(f);
                float lo = f - __uint_as_float(u & 0xFFFF0000u);
                Ah[s][j] = (short)(unsigned short)(u >> 16);
                Al[s][j] = (short)(unsigned short)(__float_as_uint(lo) >> 16);
            }
        }
        f32x4 C = {0, 0, 0, 0};
        #pragma unroll
        for (int s = 0; s < 4; ++s) {
            C = __builtin_amdgcn_mfma_f32_16x16x32_bf16(Ah[s], Bh[s], C, 0, 0, 0);
            C = __builtin_amdgcn_mfma_f32_16x16x32_bf16(Al[s], Bh[s], C, 0, 0, 0);
            C = __builtin_amdgcn_mfma_f32_16x16x32_bf16(Ah[s], Bl[s], C, 0, 0, 0);
        }
        #pragma unroll
        for (int i = 0; i < 4; ++i) {
            int R  = R0 + quad * 4 + i;
            int hh = R / 96;
            int rr = R - hh * 96;
            int hl = hh & 1;
            float f = C[i];
            if (rr < 64) {
                unsigned u = __float_as_uint(f);
                float lo = f - __uint_as_float(u & 0xFFFF0000u);
                unsigned short hi16 = (unsigned short)(u >> 16);
                unsigned short lo16 = (unsigned short)(__float_as_uint(lo) >> 16);
                int part = (rr & 31) >> 4, d = rr & 15;
                if (rr < 32) {
                    qsh[hl][m][part * 32 + d]      = hi16;
                    qsh[hl][m][part * 32 + d + 16] = lo16;
                } else {
                    ksh[hl][m][part * 32 + d]      = hi16;
                    ksh[hl][m][part * 32 + d + 16] = lo16;
                }
            } else {
                vsh[hl][rr - 64][m] = bf_rne(f);
            }
        }
    }
    __syncthreads();

    {   // qA: per-token layout. kB: fragment-major layout (R9-verified).
        int rec = t >> 3, g = t & 7;
        int hl  = rec >> 4, i = rec & 15;
        int hh  = rh * 2 + hl;
        int n   = n0 + i;
        size_t qbase = ((size_t)hh * N_TOK + n) * 64 + g * 8;
        *(uint4*)(qA + qbase) = *(const uint4*)&qsh[hl][i][g * 8];

        int tile = n >> 6, ml = n & 63;
        int kh2 = ml >> 5, mlb = (ml >> 4) & 1, mm = ml & 15;
        int f = mlb * 2 + (g >> 2), qd = g & 3;
        size_t koff = (size_t)hh * 262144 + (size_t)tile * 4096
                    + ((kh2 * 4 + f) * 64 + qd * 16 + mm) * 8;
        *(uint4*)(kB + koff) = *(const uint4*)&ksh[hl][i][g * 8];
    }
    if (t < 128) {  // vT fragment-pair-major: two 8B granule stores per thread
        int hl = t >> 6, d = (t >> 1) & 31, half = t & 1;
        int hh = rh * 2 + hl;
        int kb = (n0 >> 3) + half;
        int tile = kb >> 3, kbl = kb & 7;
        int kh2 = kbl >> 2;
        int vf  = ((kbl >> 1) & 1) * 2 + (d >> 4);
        int mm  = d & 15;
        size_t vbase = (size_t)hh * 131072 + (size_t)tile * 2048 + kh2 * 1024
                     + (vf >> 1) * 512 + (vf & 1) * 4;
        int q0 = (kbl & 1) << 1;
        *(uint2*)(vT + vbase + (q0 * 16 + mm) * 8)       = *(const uint2*)&vsh[hl][d][half * 8];
        *(uint2*)(vT + vbase + ((q0 + 1) * 16 + mm) * 8) = *(const uint2*)&vsh[hl][d][half * 8 + 4];
    }
}

// ---------------------------------------------------------------------------
// Kernel 2: MFMA flash diff-attention v15 — R11-verified v13 with V loads
// widened to 16B via the fragment-pair layout (2x bf16x8 instead of 4x
// bf16x4; operands extracted by sub-register aliasing — zero instructions,
// same bytes -> bit-exact). Everything else verbatim R11.
// ---------------------------------------------------------------------------
__global__ __launch_bounds__(256, 4) void flash_kernel(
    const unsigned short* __restrict__ qA, const unsigned short* __restrict__ kB,
    const unsigned short* __restrict__ vT, float* __restrict__ parts)
{
    __shared__ float Obuf[2][2][16][33];                    // [qt][br][r][d+pad]
    __shared__ float lbuf[2][2][16];

    const int t    = threadIdx.x;
    const int w    = t >> 6;
    const int lane = t & 63;
    const int m    = lane & 15;
    const int quad = lane >> 4;
    const int ks   = blockIdx.x & 1;
    const int qt   = (blockIdx.x >> 1) & 127;
    const int h    = blockIdx.x >> 8;
    const int qtile = w >> 1;                 // 0..1
    const int kh    = w & 1;                  // key half within tile
    const int qbase = qt * 32;

    for (int i = t; i < 2112; i += 256) ((float*)Obuf)[i] = 0.f;
    if (t < 64) ((float*)lbuf)[t] = 0.f;
    __syncthreads();   // protect Obuf init (only barrier besides readout)

    const unsigned short* qrec = qA + (size_t)(h * N_TOK + qbase + qtile * 16 + m) * 64;
    const bf16x8 zz = {0,0,0,0,0,0,0,0};
    bf16x8 Bq1h = *(const bf16x8*)(qrec + (quad & 1) * 8);
    bf16x8 Bq2h = *(const bf16x8*)(qrec + 32 + (quad & 1) * 8);
    bf16x8 Bq1l = (quad < 2) ? *(const bf16x8*)(qrec + 16 + quad * 8) : zz;
    bf16x8 Bq2l = (quad < 2) ? *(const bf16x8*)(qrec + 48 + quad * 8) : zz;

    f32x4 O1a = {0,0,0,0}, O1b = {0,0,0,0}, O2a = {0,0,0,0}, O2b = {0,0,0,0};
    float l1 = 0.f, l2 = 0.f;

    // fragment-major bases: K chunk (kh*4+f)*512 shorts; V pair (kh*2+p)*512
    const unsigned short* kt = kB + (size_t)h * 262144 + (size_t)ks * 131072;
    const unsigned short* vt = vT + (size_t)h * 131072 + (size_t)ks * 65536;
    const int kcb = kh * 2048 + lane * 8;     // + f*512 + tile*4096
    const int vcb = kh * 1024 + lane * 8;     // + p*512 + tile*2048

    bf16x8 Ka0, Ka1, Ka2, Ka3, Kb0, Kb1, Kb2, Kb3;
    bf16x8 Wa0, Wa1, Wb0, Wb1;                // V pairs: W0 = {V00,V10}, W1 = {V01,V11}

#define LOADSET(K0, K1, K2, K3, W0, W1, TILE)                                  \
    {                                                                          \
        const unsigned short* kp = kt + (size_t)(TILE) * 4096 + kcb;           \
        const unsigned short* vp = vt + (size_t)(TILE) * 2048 + vcb;           \
        K0 = *(const bf16x8*)(kp);                                             \
        K1 = *(const bf16x8*)(kp + 512);                                       \
        K2 = *(const bf16x8*)(kp + 1024);                                      \
        K3 = *(const bf16x8*)(kp + 1536);                                      \
        W0 = *(const bf16x8*)(vp);                                             \
        W1 = *(const bf16x8*)(vp + 512);                                       \
    }

    auto compute = [&](bf16x8 K1_0, bf16x8 K2_0, bf16x8 K1_1, bf16x8 K2_1,
                       bf16x8 W0, bf16x8 W1) {
        __builtin_amdgcn_s_setprio(1);
        f32x4 sA1 = {0,0,0,0}, sA2 = {0,0,0,0};
        f32x4 sB1 = {0,0,0,0}, sB2 = {0,0,0,0};
        sA1 = __builtin_amdgcn_mfma_f32_16x16x32_bf16(K1_0, Bq1h, sA1, 0, 0, 0);
        sB1 = __builtin_amdgcn_mfma_f32_16x16x32_bf16(K1_1, Bq1h, sB1, 0, 0, 0);
        sA1 = __builtin_amdgcn_mfma_f32_16x16x32_bf16(K1_0, Bq1l, sA1, 0, 0, 0);
        sB1 = __builtin_amdgcn_mfma_f32_16x16x32_bf16(K1_1, Bq1l, sB1, 0, 0, 0);
        sA2 = __builtin_amdgcn_mfma_f32_16x16x32_bf16(K2_0, Bq2h, sA2, 0, 0, 0);
        sB2 = __builtin_amdgcn_mfma_f32_16x16x32_bf16(K2_1, Bq2h, sB2, 0, 0, 0);
        sA2 = __builtin_amdgcn_mfma_f32_16x16x32_bf16(K2_0, Bq2l, sA2, 0, 0, 0);
        sB2 = __builtin_amdgcn_mfma_f32_16x16x32_bf16(K2_1, Bq2l, sB2, 0, 0, 0);

        float pa0 = __builtin_amdgcn_exp2f(sA1[0]), pa1 = __builtin_amdgcn_exp2f(sA1[1]);
        float pa2 = __builtin_amdgcn_exp2f(sA1[2]), pa3 = __builtin_amdgcn_exp2f(sA1[3]);
        float pb0 = __builtin_amdgcn_exp2f(sB1[0]), pb1 = __builtin_amdgcn_exp2f(sB1[1]);
        float pb2 = __builtin_amdgcn_exp2f(sB1[2]), pb3 = __builtin_amdgcn_exp2f(sB1[3]);
        float qa0 = __builtin_amdgcn_exp2f(sA2[0]), qa1 = __builtin_amdgcn_exp2f(sA2[1]);
        float qa2 = __builtin_amdgcn_exp2f(sA2[2]), qa3 = __builtin_amdgcn_exp2f(sA2[3]);
        float qb0 = __builtin_amdgcn_exp2f(sB2[0]), qb1 = __builtin_amdgcn_exp2f(sB2[1]);
        float qb2 = __builtin_amdgcn_exp2f(sB2[2]), qb3 = __builtin_amdgcn_exp2f(sB2[3]);
        l1 += (pa0 + pa1) + (pa2 + pa3) + (pb0 + pb1) + (pb2 + pb3);
        l2 += (qa0 + qa1) + (qa2 + qa3) + (qb0 + qb1) + (qb2 + qb3);
        union { unsigned u[2]; bf16x4 v; } cA1, cB1, cA2, cB2;
        cA1.u[0] = __builtin_amdgcn_perm(__float_as_uint(pa1), __float_as_uint(pa0), 0x07060302u);
        cA1.u[1] = __builtin_amdgcn_perm(__float_as_uint(pa3), __float_as_uint(pa2), 0x07060302u);
        cB1.u[0] = __builtin_amdgcn_perm(__float_as_uint(pb1), __float_as_uint(pb0), 0x07060302u);
        cB1.u[1] = __builtin_amdgcn_perm(__float_as_uint(pb3), __float_as_uint(pb2), 0x07060302u);
        cA2.u[0] = __builtin_amdgcn_perm(__float_as_uint(qa1), __float_as_uint(qa0), 0x07060302u);
        cA2.u[1] = __builtin_amdgcn_perm(__float_as_uint(qa3), __float_as_uint(qa2), 0x07060302u);
        cB2.u[0] = __builtin_amdgcn_perm(__float_as_uint(qb1), __float_as_uint(qb0), 0x07060302u);
        cB2.u[1] = __builtin_amdgcn_perm(__float_as_uint(qb3), __float_as_uint(qb2), 0x07060302u);

        bf16x4 V00 = __builtin_shufflevector(W0, W0, 0, 1, 2, 3);
        bf16x4 V10 = __builtin_shufflevector(W0, W0, 4, 5, 6, 7);
        bf16x4 V01 = __builtin_shufflevector(W1, W1, 0, 1, 2, 3);
        bf16x4 V11 = __builtin_shufflevector(W1, W1, 4, 5, 6, 7);

        O1a = __builtin_amdgcn_mfma_f32_16x16x16bf16_1k(cA1.v, V00, O1a, 0, 0, 0);
        O1b = __builtin_amdgcn_mfma_f32_16x16x16bf16_1k(cA1.v, V10, O1b, 0, 0, 0);
        O2a = __builtin_amdgcn_mfma_f32_16x16x16bf16_1k(cA2.v, V00, O2a, 0, 0, 0);
        O2b = __builtin_amdgcn_mfma_f32_16x16x16bf16_1k(cA2.v, V10, O2b, 0, 0, 0);
        O1a = __builtin_amdgcn_mfma_f32_16x16x16bf16_1k(cB1.v, V01, O1a, 0, 0, 0);
        O1b = __builtin_amdgcn_mfma_f32_16x16x16bf16_1k(cB1.v, V11, O1b, 0, 0, 0);
        O2a = __builtin_amdgcn_mfma_f32_16x16x16bf16_1k(cB2.v, V01, O2a, 0, 0, 0);
        O2b = __builtin_amdgcn_mfma_f32_16x16x16bf16_1k(cB2.v, V11, O2b, 0, 0, 0);
        __builtin_amdgcn_s_setprio(0);
    };

    LOADSET(Ka0, Ka1, Ka2, Ka3, Wa0, Wa1, 0);
    for (int tile = 0; tile < 32; tile += 2) {
        LOADSET(Kb0, Kb1, Kb2, Kb3, Wb0, Wb1, tile + 1);
        compute(Ka0, Ka1, Ka2, Ka3, Wa0, Wa1);
        if (tile + 2 < 32)
            LOADSET(Ka0, Ka1, Ka2, Ka3, Wa0, Wa1, tile + 2);
        compute(Kb0, Kb1, Kb2, Kb3, Wb0, Wb1);
    }
#undef LOADSET

    l1 += __shfl_xor(l1, 16, 64); l1 += __shfl_xor(l1, 32, 64);
    l2 += __shfl_xor(l2, 16, 64); l2 += __shfl_xor(l2, 32, 64);
    if (lane < 16) {
        atomicAdd(&lbuf[qtile][0][m], l1);
        atomicAdd(&lbuf[qtile][1][m], l2);
    }
    #pragma unroll
    for (int i = 0; i < 4; ++i) {
        int r = quad * 4 + i;
        atomicAdd(&Obuf[qtile][0][r][m],      O1a[i]);
        atomicAdd(&Obuf[qtile][0][r][16 + m], O1b[i]);
        atomicAdd(&Obuf[qtile][1][r][m],      O2a[i]);
        atomicAdd(&Obuf[qtile][1][r][16 + m], O2b[i]);
    }
    __syncthreads();

    float* dst = parts + (size_t)((h * 128 + qt) * 2 + ks) * PSTRIDE;
    for (int i = t; i < 1024; i += 256) {
        int r = i >> 5, d = i & 31;
        int qtl = r >> 4, rl = r & 15;
        dst[i]        = Obuf[qtl][0][rl][d];
        dst[1024 + i] = Obuf[qtl][1][rl][d];
    }
    if (t < 32) {
        int qtl = t >> 4, rl = t & 15;
        dst[2048 + t] = lbuf[qtl][0][rl];
        dst[2080 + t] = lbuf[qtl][1][rl];
    }
}

// ---------------------------------------------------------------------------
// Kernel 3: split-K merge + finalize, float4-vectorized (verbatim R11).
// ---------------------------------------------------------------------------
__global__ __launch_bounds__(256) void merge_kernel(
    const float* __restrict__ parts, float* __restrict__ out)
{
    int idx = blockIdx.x * 256 + threadIdx.x;     // 131072 threads
    int d4 = (idx & 7) * 4;
    int row = idx >> 3;
    int h = row >> 12, n = row & 4095;
    int qt = n >> 5, r = n & 31;
    const float* p0 = parts + (size_t)((h * 128 + qt) * 2) * PSTRIDE;
    const float* p1 = p0 + PSTRIDE;
    float4 a1 = *(const float4*)(p0 + r * 32 + d4);
    float4 b1 = *(const float4*)(p1 + r * 32 + d4);
    float4 a2 = *(const float4*)(p0 + 1024 + r * 32 + d4);
    float4 b2 = *(const float4*)(p1 + 1024 + r * 32 + d4);
    float l1 = p0[2048 + r] + p1[2048 + r];
    float l2 = p0[2080 + r] + p1[2080 + r];
    float4 o;
    o.x = (a1.x + b1.x) / l1 - LAMBDA_ * ((a2.x + b2.x) / l2);
    o.y = (a1.y + b1.y) / l1 - LAMBDA_ * ((a2.y + b2.y) / l2);
    o.z = (a1.z + b1.z) / l1 - LAMBDA_ * ((a2.z + b2.z) / l2);
    o.w = (a1.w + b1.w) / l1 - LAMBDA_ * ((a2.w + b2.w) / l2);
    *(float4*)(out + (size_t)idx * 4) = o;
}

extern "C" void kernel_launch(void* const* d_in, const int* in_sizes, int n_in,
                              void* d_out, int out_size, void* d_ws, size_t ws_size,
                              hipStream_t stream) {
    const float* x = (const float*)d_in[0];   // (1,128,32,32,32)
    const float* w = (const float*)d_in[1];   // (384,128)
    float* out = (float*)d_out;               // [h][n][32] flat

    unsigned short* qA = (unsigned short*)d_ws;               // 2 MB
    unsigned short* kB = qA + (size_t)NH * N_TOK * 64;        // 2 MB
    unsigned short* vT = kB + (size_t)NH * N_TOK * 64;        // 1 MB
    float* parts = (float*)(vT + (size_t)NH * 32 * N_TOK);    // 1024*2112*4B = 8.65 MB

    qkv_kernel<<<512, 256, 0, stream>>>(x, w, qA, kB, vT);
    flash_kernel<<<1024, 256, 0, stream>>>(qA, kB, vT, parts);
    merge_kernel<<<512, 256, 0, stream>>>(parts, out);
}